// Round 6
// baseline (350.621 us; speedup 1.0000x reference)
//
#include <hip/hip_runtime.h>
#include <cstdint>

#pragma clang fp contract(off)

#define BS   128
#define NQ   900
#define NC   91
#define NQC  (NQ * NC)   // 81900
#define Q4   (NQC / 4)   // 20475
#define PRE  10000
#define POST 100
#define SEGA 8192
#define SEGB 4096
#define RUNSZ 4096
#define RUNS 3
#define KSTRIDE (RUNS * RUNSZ)    // 12288 keys per image
#define CNTS 16
#define TBITS 13
#define TBINS (1 << TBITS)
#define TSHIFT (32 - TBITS)
#define WPRE 320                  // ceil(PRE/32) words for active bitmask
#define K_WIN 8

typedef unsigned long long ull;

// ---- workspace layout (bytes) ----
#define WS_CNT    0            // 128*CNTS*4 = 8 KB   (zeroed)
#define WS_MX     8192         // 128*4               (zeroed)
#define WS_CCNT   16384        // 128*91*4 = 46592    (zeroed)
#define WS_HIST   65536        // 128*8192*4 = 4 MB   (zeroed)
#define WS_THR    4259840      // 128*2*4
#define WS_KEYS   4260864      // 128*12288*8 = 12 MB
#define WS_TOP    16843776     // 128*10000*8 = 10 MB
#define WS_ZERO_BYTES WS_THR   // memset [0, WS_THR)

__device__ __forceinline__ uint32_t fkey(float f) {
    uint32_t b = __float_as_uint(f);
    return (b & 0x80000000u) ? ~b : (b | 0x80000000u);
}
__device__ __forceinline__ float finv(uint32_t u) {
    uint32_t b = (u & 0x80000000u) ? (u & 0x7FFFFFFFu) : ~u;
    return __uint_as_float(b);
}
// defensive clamp: valid keys give q < NQ; turns capacity bugs into wrong-value not fault
__device__ __forceinline__ uint32_t qclamp(uint32_t q) { return (q < NQ) ? q : (NQ - 1); }

// ============ Kernel 1: partial histograms, 4 blocks/image ============
__global__ void __launch_bounds__(1024) k_hist(const float* __restrict__ logits,
                                               uint32_t* __restrict__ hist_g) {
    int img = blockIdx.y;
    int chunk = blockIdx.x;
    const int tid = threadIdx.x;
    __shared__ uint32_t hist[TBINS];   // 32 KB
    for (int i = tid; i < TBINS; i += 1024) hist[i] = 0u;
    __syncthreads();
    const float4* lg4 = (const float4*)(logits + (size_t)img * NQC);
    const int per = (Q4 + 3) / 4;              // 5119
    const int s = chunk * per;
    const int e = (s + per < Q4) ? (s + per) : Q4;
    for (int i = s + tid; i < e; i += 1024) {
        float4 v = lg4[i];
        atomicAdd(&hist[fkey(v.x) >> TSHIFT], 1u);
        atomicAdd(&hist[fkey(v.y) >> TSHIFT], 1u);
        atomicAdd(&hist[fkey(v.z) >> TSHIFT], 1u);
        atomicAdd(&hist[fkey(v.w) >> TSHIFT], 1u);
    }
    __syncthreads();
    uint32_t* gh = hist_g + (size_t)img * TBINS;
    for (int b = tid; b < TBINS; b += 1024) {
        uint32_t v = hist[b];
        if (v) atomicAdd(&gh[b], v);
    }
}

// ============ Kernel 2: thresholds from global hist ============
// T_lo: largest bin boundary with suffix >= PRE; T_hi: smallest with suffix <= SEGA.
// Rare fallback refines T_lo by 8 bits (one extra pass over this image's logits).
__global__ void __launch_bounds__(1024) k_thresh(const float* __restrict__ logits,
                                                 const uint32_t* __restrict__ hist_g,
                                                 uint32_t* __restrict__ thr) {
    int img = blockIdx.x;
    const int tid = threadIdx.x;
    __shared__ uint32_t hist[TBINS];
    __shared__ uint32_t part[1024];
    __shared__ uint32_t part2[32];
    __shared__ uint32_t sTlo, sThi, sBlo, sCumAboveLo, sM, sM1;
    const uint32_t* gh = hist_g + (size_t)img * TBINS;
    for (int i = tid; i < TBINS; i += 1024) hist[i] = gh[i];
    __syncthreads();
    {
        uint32_t s = 0;
        int base = tid * (TBINS / 1024);
        for (int j = 0; j < TBINS / 1024; ++j) s += hist[base + j];
        part[tid] = s;
    }
    __syncthreads();
    if (tid < 32) {
        uint32_t s2 = 0;
        for (int j = 0; j < 32; ++j) s2 += part[tid * 32 + j];
        part2[tid] = s2;
    }
    __syncthreads();
    if (tid == 0) {
        uint32_t cum = 0; int w = 31;
        for (; w > 0; --w) { if (cum + part2[w] >= PRE) break; cum += part2[w]; }
        int t = w * 32 + 31;
        for (; t > w * 32; --t) { if (cum + part[t] >= PRE) break; cum += part[t]; }
        int b = t * (TBINS / 1024) + (TBINS / 1024 - 1);
        for (; b > t * (TBINS / 1024); --b) { if (cum + hist[b] >= PRE) break; cum += hist[b]; }
        sBlo = (uint32_t)b;
        sCumAboveLo = cum;
        sM = cum + hist[b];
        sTlo = ((uint32_t)b) << TSHIFT;
        uint32_t cum2 = 0; int w2 = 31;
        for (; w2 >= 0; --w2) { if (cum2 + part2[w2] > SEGA) break; cum2 += part2[w2]; }
        int t2 = w2 * 32 + 31;
        for (; t2 >= w2 * 32; --t2) { if (cum2 + part[t2] > SEGA) break; cum2 += part[t2]; }
        int b2 = t2 * (TBINS / 1024) + (TBINS / 1024 - 1);
        for (; b2 >= t2 * (TBINS / 1024); --b2) { if (cum2 + hist[b2] > SEGA) break; cum2 += hist[b2]; }
        sM1 = cum2;
        sThi = (b2 >= TBINS - 1) ? 0xFFFFFFFFu : (((uint32_t)(b2 + 1)) << TSHIFT);
    }
    __syncthreads();
    if (sM - sM1 > SEGB) {   // block-uniform rare fallback
        uint32_t P = sBlo;
        for (int i = tid; i < 256; i += 1024) part[i] = 0u;
        __syncthreads();
        const float4* lg4 = (const float4*)(logits + (size_t)img * NQC);
        for (int i = tid; i < Q4; i += 1024) {
            float4 v = lg4[i];
            uint32_t u;
            u = fkey(v.x); if ((u >> TSHIFT) == P) atomicAdd(&part[(u >> (TSHIFT - 8)) & 0xFFu], 1u);
            u = fkey(v.y); if ((u >> TSHIFT) == P) atomicAdd(&part[(u >> (TSHIFT - 8)) & 0xFFu], 1u);
            u = fkey(v.z); if ((u >> TSHIFT) == P) atomicAdd(&part[(u >> (TSHIFT - 8)) & 0xFFu], 1u);
            u = fkey(v.w); if ((u >> TSHIFT) == P) atomicAdd(&part[(u >> (TSHIFT - 8)) & 0xFFu], 1u);
        }
        __syncthreads();
        if (tid == 0) {
            uint32_t K = PRE - sCumAboveLo;
            uint32_t cum = 0; int x = 255;
            for (; x > 0; --x) { if (cum + part[x] >= K) break; cum += part[x]; }
            sTlo = (P << TSHIFT) | (((uint32_t)x) << (TSHIFT - 8));
        }
        __syncthreads();
    }
    if (tid == 0) { thr[img * 2 + 0] = sTlo; thr[img * 2 + 1] = sThi; }
}

// ============ Kernel 3: two-way compaction, 20 blocks/image, block-aggregated atomics ============
__global__ void __launch_bounds__(1024) k_compact(const float* __restrict__ logits,
                                                  const uint32_t* __restrict__ thr,
                                                  uint32_t* __restrict__ cnt,
                                                  ull* __restrict__ keys) {
    int img = blockIdx.y;
    const int tid = threadIdx.x;
    const int lane = tid & 63;
    __shared__ uint32_t sA, sB, gA, gB;
    if (tid == 0) { sA = 0u; sB = 0u; }
    __syncthreads();
    const uint32_t Tlo = thr[img * 2 + 0], Thi = thr[img * 2 + 1];
    const float* lg = logits + (size_t)img * NQC;
    const int base = blockIdx.x * 4096 + tid;

    uint32_t ukey[4]; bool fa[4], fb[4];
    uint32_t belowA[4], belowB[4], tAr[4], tBr[4];
    uint32_t TA = 0u, TB = 0u;
    #pragma unroll
    for (int r = 0; r < 4; ++r) {
        int i = base + r * 1024;
        uint32_t u = 0u; bool a = false, b = false;
        if (i < NQC) {
            u = fkey(lg[i]);
            a = (u >= Thi);
            b = !a && (u >= Tlo);
        }
        ukey[r] = u; fa[r] = a; fb[r] = b;
        ull ma = __ballot(a), mb = __ballot(b);
        belowA[r] = (uint32_t)__popcll(ma & ((1ull << lane) - 1ull));
        belowB[r] = (uint32_t)__popcll(mb & ((1ull << lane) - 1ull));
        tAr[r] = (uint32_t)__popcll(ma);
        tBr[r] = (uint32_t)__popcll(mb);
        TA += tAr[r]; TB += tBr[r];
    }
    uint32_t wbA = 0u, wbB = 0u;
    if (lane == 0) {
        if (TA) wbA = atomicAdd(&sA, TA);
        if (TB) wbB = atomicAdd(&sB, TB);
    }
    wbA = __shfl(wbA, 0, 64);
    wbB = __shfl(wbB, 0, 64);
    __syncthreads();
    if (tid == 0) {
        gA = sA ? atomicAdd(&cnt[img * CNTS + 0], sA) : 0u;
        gB = sB ? atomicAdd(&cnt[img * CNTS + 1], sB) : 0u;
    }
    __syncthreads();
    ull* kI = keys + (size_t)img * KSTRIDE;
    uint32_t preA = 0u, preB = 0u;
    #pragma unroll
    for (int r = 0; r < 4; ++r) {
        int i = base + r * 1024;
        ull kv = ((ull)ukey[r] << 32) | (ull)(0xFFFFFFFFu - (uint32_t)i);
        if (fa[r]) { uint32_t p = gA + wbA + preA + belowA[r]; if (p < SEGA) kI[p] = kv; }
        if (fb[r]) { uint32_t p = gB + wbB + preB + belowB[r]; if (p < SEGB) kI[SEGA + p] = kv; }
        preA += tAr[r]; preB += tBr[r];
    }
}

// ============ Kernel 4: bitonic sort of 3 runs of 4096 (desc), zero-padded ============
__global__ void __launch_bounds__(1024) k_sortrun(ull* __restrict__ keys,
                                                  const uint32_t* __restrict__ cnt) {
    int img = blockIdx.y;
    int run = blockIdx.x;
    const int tid = threadIdx.x;
    uint32_t cntA = cnt[img * CNTS + 0]; if (cntA > SEGA) cntA = SEGA;
    uint32_t cntB = cnt[img * CNTS + 1]; if (cntB > SEGB) cntB = SEGB;
    int n = (run == 0) ? ((cntA < RUNSZ) ? (int)cntA : RUNSZ)
          : (run == 1) ? ((cntA > RUNSZ) ? (int)(cntA - RUNSZ) : 0)
                       : (int)cntB;
    ull* base = keys + (size_t)img * KSTRIDE + (size_t)run * RUNSZ;
    __shared__ ull sh[RUNSZ];   // 32 KB
    for (int i = tid; i < RUNSZ; i += 1024) sh[i] = (i < n) ? base[i] : 0ull;
    __syncthreads();
    for (int k = 2; k <= RUNSZ; k <<= 1) {
        for (int j = k >> 1; j > 0; j >>= 1) {
            for (int t = tid; t < RUNSZ / 2; t += 1024) {
                int i = ((t & ~(j - 1)) << 1) | (t & (j - 1));
                int ixj = i | j;
                ull a = sh[i], b = sh[ixj];
                bool sw = ((i & k) == 0) ? (a < b) : (a > b);
                if (sw) { sh[i] = b; sh[ixj] = a; }
            }
            __syncthreads();
        }
    }
    for (int i = tid; i < RUNSZ; i += 1024) base[i] = sh[i];
}

// ============ Kernel 5: 3-way rank merge -> exact sorted top[PRE]; class counts + max coord ============
__global__ void __launch_bounds__(256) k_merge(const ull* __restrict__ keys,
                                               const float* __restrict__ pred_boxes,
                                               const float* __restrict__ target_sizes,
                                               ull* __restrict__ top,
                                               uint32_t* __restrict__ ccnt_g,
                                               uint32_t* __restrict__ mxkey) {
    int img = blockIdx.y;
    int e = blockIdx.x * 256 + threadIdx.x;    // [0, KSTRIDE)
    const int tid = threadIdx.x;
    const ull* kI = keys + (size_t)img * KSTRIDE;
    __shared__ uint32_t smx[256];
    uint32_t lm = 0u;
    ull x = kI[e];
    if (x != 0ull) {
        int run = e >> 12;
        int pos = e & (RUNSZ - 1);
        int rank = pos;
        #pragma unroll
        for (int s = 0; s < RUNS; ++s) {
            if (s != run) {
                const ull* o = kI + s * RUNSZ;
                int lo = 0, hi = RUNSZ;
                while (lo < hi) {
                    int mid = (lo + hi) >> 1;
                    if (o[mid] > x) lo = mid + 1; else hi = mid;
                }
                rank += lo;
            }
        }
        if (rank < PRE) {
            top[(size_t)img * PRE + rank] = x;
            uint32_t f = ~(uint32_t)x;
            uint32_t q = qclamp(f / NC);
            uint32_t c = f - (f / NC) * NC;
            atomicAdd(&ccnt_g[img * NC + (c % NC)], 1u);
            const float* pb = pred_boxes + (size_t)img * NQ * 4;
            const float ih = target_sizes[img * 2 + 0];
            const float iw = target_sizes[img * 2 + 1];
            float cx = pb[q * 4 + 0], cy = pb[q * 4 + 1], w = pb[q * 4 + 2], h = pb[q * 4 + 3];
            float x1 = (cx - 0.5f * w) * iw;
            float y1 = (cy - 0.5f * h) * ih;
            float x2 = (cx + 0.5f * w) * iw;
            float y2 = (cy + 0.5f * h) * ih;
            float m = fmaxf(fmaxf(x1, y1), fmaxf(x2, y2));
            lm = fkey(m);
        }
    }
    smx[tid] = lm;
    __syncthreads();
    for (int s = 128; s > 0; s >>= 1) {
        if (tid < s) { uint32_t o = smx[tid + s]; if (o > smx[tid]) smx[tid] = o; }
        __syncthreads();
    }
    if (tid == 0 && smx[0]) atomicMax(&mxkey[img], smx[0]);
}

// ============ Kernel 6: windowed greedy NMS with class buckets ============
// Cross-class suppression provably impossible (offset bands: inter <= area/4 => IoU <= 1/3
// < 0.7), so suppression scans only accepted candidates' class buckets (~110 items each).
__global__ void __launch_bounds__(1024) k_nms(const ull* __restrict__ top,
                                              const float* __restrict__ pred_boxes,
                                              const float* __restrict__ target_sizes,
                                              const uint32_t* __restrict__ ccnt_g,
                                              const uint32_t* __restrict__ mxkey,
                                              float* __restrict__ out) {
    int img = blockIdx.x;
    const int tid = threadIdx.x;
    __shared__ uint32_t fidx[PRE];          // 40000 B
    __shared__ unsigned short clist[PRE];   // 20000 B
    __shared__ uint32_t actw[WPRE];
    __shared__ uint32_t ccnt[NC];
    __shared__ uint32_t cstart[NC + 1];
    __shared__ uint32_t cfill[NC];
    __shared__ float sOffD;
    __shared__ int   s_cand[K_WIN];
    __shared__ float s_cx1[K_WIN], s_cy1[K_WIN], s_cx2[K_WIN], s_cy2[K_WIN], s_car[K_WIN];
    __shared__ int   s_ccl[K_WIN], s_cbs[K_WIN], s_cbe[K_WIN];

    const float ih = target_sizes[img * 2 + 0];
    const float iw = target_sizes[img * 2 + 1];
    const float* pb = pred_boxes + (size_t)img * NQ * 4;
    const ull* tp = top + (size_t)img * PRE;

    // Phase 1: pure loads (boxes/max/class-counts precomputed in k_merge)
    #pragma unroll
    for (int k = 0; k < 10; ++k) {
        int r = tid + k * 1024;
        if (r < PRE) fidx[r] = ~(uint32_t)tp[r];
    }
    for (int c = tid; c < NC; c += 1024) ccnt[c] = ccnt_g[img * NC + c];
    for (int wI = tid; wI < WPRE; wI += 1024) {
        int base = wI * 32;
        uint32_t m = 0xFFFFFFFFu;
        if (base + 32 > PRE) m = (base >= PRE) ? 0u : (0xFFFFFFFFu >> (base + 32 - PRE));
        actw[wI] = m;
    }
    __syncthreads();
    if (tid == 0) {
        sOffD = finv(mxkey[img]) + 1.0f;   // max_coord + 1
        uint32_t run = 0;
        for (int c = 0; c < NC; ++c) { cstart[c] = run; cfill[c] = run; run += ccnt[c]; }
        cstart[NC] = run;
    }
    __syncthreads();
    const float offD = sOffD;

    #pragma unroll
    for (int k = 0; k < 10; ++k) {
        int r = tid + k * 1024;
        if (r < PRE) {
            uint32_t c = fidx[r] % NC;
            uint32_t pos = atomicAdd(&cfill[c], 1u);
            if (pos < PRE) clist[pos] = (unsigned short)r;
        }
    }
    __syncthreads();

    // Phase 3: windowed greedy picks
    int wstart = 0;
    int pick = 0;
    while (pick < POST) {
        while (wstart < WPRE && actw[wstart] == 0u) ++wstart;   // uniform
        if (wstart >= WPRE) {
            uint32_t fi = fidx[0];
            uint32_t qi = qclamp(fi / NC);
            uint32_t ci = fi - (fi / NC) * NC;
            float cx = pb[qi * 4 + 0], cy = pb[qi * 4 + 1], w = pb[qi * 4 + 2], h = pb[qi * 4 + 3];
            float rx1 = (cx - 0.5f * w) * iw;
            float ry1 = (cy - 0.5f * h) * ih;
            float rx2 = (cx + 0.5f * w) * iw;
            float ry2 = (cy + 0.5f * h) * ih;
            ull key = tp[0];
            uint32_t u = (uint32_t)(key >> 32);
            float score = 1.0f / (1.0f + expf(-finv(u)));
            for (int p = pick + tid; p < POST; p += 1024) {
                out[img * POST + p] = score;
                out[BS * POST + img * POST + p] = (float)ci;
                float* ob = out + 2 * BS * POST + ((size_t)img * POST + p) * 4;
                ob[0] = rx1; ob[1] = ry1; ob[2] = rx2; ob[3] = ry2;
            }
            break;
        }

        int ncand = 0;
        int myr = -1;
        {
            int wI = wstart;
            uint32_t wbits = actw[wI];
            #pragma unroll
            for (int j = 0; j < K_WIN; ++j) {
                while (wbits == 0u && wI + 1 < WPRE) { ++wI; wbits = actw[wI]; }
                if (wbits) {
                    int r = wI * 32 + (__ffs(wbits) - 1);
                    wbits &= wbits - 1u;
                    if (tid == 0) s_cand[j] = r;
                    if (tid == j) myr = r;
                    ++ncand;
                }
            }
        }

        if (tid < ncand) {
            uint32_t fi = fidx[myr];
            uint32_t q = qclamp(fi / NC);
            int c = (int)(fi - (fi / NC) * NC);
            float cx = pb[q * 4 + 0], cy = pb[q * 4 + 1], w = pb[q * 4 + 2], h = pb[q * 4 + 3];
            float x1 = (cx - 0.5f * w) * iw;
            float y1 = (cy - 0.5f * h) * ih;
            float x2 = (cx + 0.5f * w) * iw;
            float y2 = (cy + 0.5f * h) * ih;
            float o = (float)c * offD;
            float a1 = x1 + o, b1 = y1 + o, a2 = x2 + o, b2 = y2 + o;
            s_cx1[tid] = a1; s_cy1[tid] = b1; s_cx2[tid] = a2; s_cy2[tid] = b2;
            s_car[tid] = (a2 - a1) * (b2 - b1);
            s_ccl[tid] = c;
            s_cbs[tid] = (int)cstart[(c >= 0 && c < NC) ? c : 0];
            s_cbe[tid] = (int)cstart[((c >= 0 && c < NC) ? c : 0) + 1];
        }
        __syncthreads();

        float cx1[K_WIN], cy1[K_WIN], cx2[K_WIN], cy2[K_WIN], car_[K_WIN];
        #pragma unroll
        for (int j = 0; j < K_WIN; ++j) {
            bool v = (j < ncand);
            cx1[j] = v ? s_cx1[j] : 0.0f;
            cy1[j] = v ? s_cy1[j] : 0.0f;
            cx2[j] = v ? s_cx2[j] : 0.0f;
            cy2[j] = v ? s_cy2[j] : 0.0f;
            car_[j] = v ? s_car[j] : 0.0f;
        }

        uint32_t accMask = 0u;
        int A = 0;
        const int maxA = POST - pick;
        #pragma unroll
        for (int j = 0; j < K_WIN; ++j) {
            if (j < ncand && A < maxA) {
                bool ok = true;
                #pragma unroll
                for (int m = 0; m < K_WIN; ++m) {
                    if (m < j && ((accMask >> m) & 1u)) {
                        float xx1 = fmaxf(cx1[m], cx1[j]);
                        float yy1 = fmaxf(cy1[m], cy1[j]);
                        float xx2 = fminf(cx2[m], cx2[j]);
                        float yy2 = fminf(cy2[m], cy2[j]);
                        float inter = fmaxf(xx2 - xx1, 0.0f) * fmaxf(yy2 - yy1, 0.0f);
                        float uni = (car_[m] + car_[j]) - inter;
                        float iou = inter / fmaxf(uni, 1e-9f);
                        if (!(iou <= 0.7f)) ok = false;
                    }
                }
                if (ok) { accMask |= (1u << j); ++A; }
            }
        }

        #pragma unroll
        for (int j = 0; j < K_WIN; ++j) {
            if ((accMask >> j) & 1u) {
                int ord = __popc(accMask & ((1u << j) - 1u));
                if (tid == ord) {
                    int r = s_cand[j];
                    uint32_t fi = fidx[r];
                    uint32_t qi = qclamp(fi / NC);
                    uint32_t ci = fi - (fi / NC) * NC;
                    float cx = pb[qi * 4 + 0], cy = pb[qi * 4 + 1], w = pb[qi * 4 + 2], h = pb[qi * 4 + 3];
                    float rx1 = (cx - 0.5f * w) * iw;
                    float ry1 = (cy - 0.5f * h) * ih;
                    float rx2 = (cx + 0.5f * w) * iw;
                    float ry2 = (cy + 0.5f * h) * ih;
                    ull key = tp[r];
                    uint32_t u = (uint32_t)(key >> 32);
                    float score = 1.0f / (1.0f + expf(-finv(u)));
                    int p = pick + ord;
                    out[img * POST + p] = score;
                    out[BS * POST + img * POST + p] = (float)ci;
                    float* ob = out + 2 * BS * POST + ((size_t)img * POST + p) * 4;
                    ob[0] = rx1; ob[1] = ry1; ob[2] = rx2; ob[3] = ry2;
                }
            }
        }

        #pragma unroll
        for (int j = 0; j < K_WIN; ++j) {
            if ((accMask >> j) & 1u) {
                int bs = s_cbs[j], be = s_cbe[j];
                float o = (float)s_ccl[j] * offD;
                for (int t2 = bs + tid; t2 < be; t2 += 1024) {
                    int r2 = clist[t2];
                    if (actw[r2 >> 5] & (1u << (r2 & 31))) {
                        uint32_t f2 = fidx[r2];
                        uint32_t q2 = qclamp(f2 / NC);
                        float cx = pb[q2 * 4 + 0], cy = pb[q2 * 4 + 1], w = pb[q2 * 4 + 2], h = pb[q2 * 4 + 3];
                        float jx1 = (cx - 0.5f * w) * iw + o;
                        float jy1 = (cy - 0.5f * h) * ih + o;
                        float jx2 = (cx + 0.5f * w) * iw + o;
                        float jy2 = (cy + 0.5f * h) * ih + o;
                        float arj = (jx2 - jx1) * (jy2 - jy1);
                        float xx1 = fmaxf(cx1[j], jx1);
                        float yy1 = fmaxf(cy1[j], jy1);
                        float xx2 = fminf(cx2[j], jx2);
                        float yy2 = fminf(cy2[j], jy2);
                        float inter = fmaxf(xx2 - xx1, 0.0f) * fmaxf(yy2 - yy1, 0.0f);
                        float uni = (car_[j] + arj) - inter;
                        float iou = inter / fmaxf(uni, 1e-9f);
                        if (!(iou <= 0.7f)) atomicAnd(&actw[r2 >> 5], ~(1u << (r2 & 31)));
                    }
                }
            }
        }
        pick += A;
        __syncthreads();
    }
}

extern "C" void kernel_launch(void* const* d_in, const int* in_sizes, int n_in,
                              void* d_out, int out_size, void* d_ws, size_t ws_size,
                              hipStream_t stream) {
    const float* logits = (const float*)d_in[0];
    const float* boxes  = (const float*)d_in[1];
    const float* tsizes = (const float*)d_in[2];
    float* out = (float*)d_out;

    char* ws = (char*)d_ws;
    uint32_t* cnt    = (uint32_t*)(ws + WS_CNT);
    uint32_t* mxk    = (uint32_t*)(ws + WS_MX);
    uint32_t* ccnt_g = (uint32_t*)(ws + WS_CCNT);
    uint32_t* hist_g = (uint32_t*)(ws + WS_HIST);
    uint32_t* thr    = (uint32_t*)(ws + WS_THR);
    ull* keys = (ull*)(ws + WS_KEYS);
    ull* top  = (ull*)(ws + WS_TOP);

    hipMemsetAsync(ws, 0, WS_ZERO_BYTES, stream);
    k_hist<<<dim3(4, BS), 1024, 0, stream>>>(logits, hist_g);
    k_thresh<<<BS, 1024, 0, stream>>>(logits, hist_g, thr);
    k_compact<<<dim3(20, BS), 1024, 0, stream>>>(logits, thr, cnt, keys);
    k_sortrun<<<dim3(RUNS, BS), 1024, 0, stream>>>(keys, cnt);
    k_merge<<<dim3(KSTRIDE / 256, BS), 256, 0, stream>>>(keys, boxes, tsizes, top, ccnt_g, mxk);
    k_nms<<<BS, 1024, 0, stream>>>(top, boxes, tsizes, ccnt_g, mxk, out);
}

// Round 7
// 295.134 us; speedup vs baseline: 1.1880x; 1.1880x over previous
//
#include <hip/hip_runtime.h>
#include <cstdint>

#pragma clang fp contract(off)

#define BS   128
#define NQ   900
#define NC   91
#define NQC  (NQ * NC)   // 81900
#define Q4   (NQC / 4)   // 20475
#define PRE  10000
#define POST 100
#define SEGA 8192
#define SEGB 4096
#define RUNSZ 4096
#define RUNS 3
#define KSTRIDE (RUNS * RUNSZ)    // 12288 keys per image
#define CNTS 16
#define TBITS 13
#define TBINS (1 << TBITS)
#define TSHIFT (32 - TBITS)
#define WPRE 320                  // ceil(PRE/32) words for active bitmask
#define K_WIN 8

typedef unsigned long long ull;

// ---- workspace layout (bytes); zeroing done in k_select (no memset kernel) ----
#define WS_CNT    0            // 128*CNTS*4 = 8 KB
#define WS_MX     8192         // 128*4
#define WS_CCNT   16384        // 128*91*4 = 46592
#define WS_THR    65536        // 128*2*4 = 1024
#define WS_KEYS   66560        // 128*12288*8 = 12 MB
#define WS_TOP    12649472     // 128*10000*8 = 10.24 MB

__device__ __forceinline__ uint32_t fkey(float f) {
    uint32_t b = __float_as_uint(f);
    return (b & 0x80000000u) ? ~b : (b | 0x80000000u);
}
__device__ __forceinline__ float finv(uint32_t u) {
    uint32_t b = (u & 0x80000000u) ? (u & 0x7FFFFFFFu) : ~u;
    return __uint_as_float(b);
}
// defensive clamp: valid keys give q < NQ; turns capacity bugs into wrong-value not fault
__device__ __forceinline__ uint32_t qclamp(uint32_t q) { return (q < NQ) ? q : (NQ - 1); }

// ============ Kernel 1: per-image LDS histogram -> thresholds; zero counters ============
// T_lo: largest bin boundary with suffix >= PRE; T_hi: smallest with suffix <= SEGA.
// Segment A: key >= T_hi (<= 8192). Segment B: [T_lo, T_hi) (~1940 typ, <= 4096;
// rare 8-bit refine if the straddling bin is fat). Sorted concat == sorted merge.
__global__ void __launch_bounds__(1024) k_select(const float* __restrict__ logits,
                                                 uint32_t* __restrict__ cnt,
                                                 uint32_t* __restrict__ ccnt_g,
                                                 uint32_t* __restrict__ mxkey,
                                                 uint32_t* __restrict__ thr) {
    int img = blockIdx.x;
    const int tid = threadIdx.x;
    __shared__ uint32_t hist[TBINS];   // 32 KB
    __shared__ uint32_t part[1024];
    __shared__ uint32_t part2[32];
    __shared__ uint32_t sTlo, sThi, sBlo, sCumAboveLo, sM, sM1;
    for (int i = tid; i < TBINS; i += 1024) hist[i] = 0u;
    if (tid == 0) { cnt[img * CNTS + 0] = 0u; cnt[img * CNTS + 1] = 0u; mxkey[img] = 0u; }
    for (int c = tid; c < NC; c += 1024) ccnt_g[img * NC + c] = 0u;
    __syncthreads();
    const float4* lg4 = (const float4*)(logits + (size_t)img * NQC);
    for (int i = tid; i < Q4; i += 1024) {
        float4 v = lg4[i];
        atomicAdd(&hist[fkey(v.x) >> TSHIFT], 1u);
        atomicAdd(&hist[fkey(v.y) >> TSHIFT], 1u);
        atomicAdd(&hist[fkey(v.z) >> TSHIFT], 1u);
        atomicAdd(&hist[fkey(v.w) >> TSHIFT], 1u);
    }
    __syncthreads();
    {
        uint32_t s = 0;
        int base = tid * (TBINS / 1024);
        for (int j = 0; j < TBINS / 1024; ++j) s += hist[base + j];
        part[tid] = s;
    }
    __syncthreads();
    if (tid < 32) {
        uint32_t s2 = 0;
        for (int j = 0; j < 32; ++j) s2 += part[tid * 32 + j];
        part2[tid] = s2;
    }
    __syncthreads();
    if (tid == 0) {
        uint32_t cum = 0; int w = 31;
        for (; w > 0; --w) { if (cum + part2[w] >= PRE) break; cum += part2[w]; }
        int t = w * 32 + 31;
        for (; t > w * 32; --t) { if (cum + part[t] >= PRE) break; cum += part[t]; }
        int b = t * (TBINS / 1024) + (TBINS / 1024 - 1);
        for (; b > t * (TBINS / 1024); --b) { if (cum + hist[b] >= PRE) break; cum += hist[b]; }
        sBlo = (uint32_t)b;
        sCumAboveLo = cum;
        sM = cum + hist[b];
        sTlo = ((uint32_t)b) << TSHIFT;
        uint32_t cum2 = 0; int w2 = 31;
        for (; w2 >= 0; --w2) { if (cum2 + part2[w2] > SEGA) break; cum2 += part2[w2]; }
        int t2 = w2 * 32 + 31;
        for (; t2 >= w2 * 32; --t2) { if (cum2 + part[t2] > SEGA) break; cum2 += part[t2]; }
        int b2 = t2 * (TBINS / 1024) + (TBINS / 1024 - 1);
        for (; b2 >= t2 * (TBINS / 1024); --b2) { if (cum2 + hist[b2] > SEGA) break; cum2 += hist[b2]; }
        sM1 = cum2;
        sThi = (b2 >= TBINS - 1) ? 0xFFFFFFFFu : (((uint32_t)(b2 + 1)) << TSHIFT);
    }
    __syncthreads();
    if (sM - sM1 > SEGB) {   // block-uniform rare fallback: refine Tlo by 8 bits
        uint32_t P = sBlo;
        for (int i = tid; i < 256; i += 1024) part[i] = 0u;
        __syncthreads();
        for (int i = tid; i < Q4; i += 1024) {
            float4 v = lg4[i];
            uint32_t u;
            u = fkey(v.x); if ((u >> TSHIFT) == P) atomicAdd(&part[(u >> (TSHIFT - 8)) & 0xFFu], 1u);
            u = fkey(v.y); if ((u >> TSHIFT) == P) atomicAdd(&part[(u >> (TSHIFT - 8)) & 0xFFu], 1u);
            u = fkey(v.z); if ((u >> TSHIFT) == P) atomicAdd(&part[(u >> (TSHIFT - 8)) & 0xFFu], 1u);
            u = fkey(v.w); if ((u >> TSHIFT) == P) atomicAdd(&part[(u >> (TSHIFT - 8)) & 0xFFu], 1u);
        }
        __syncthreads();
        if (tid == 0) {
            uint32_t K = PRE - sCumAboveLo;
            uint32_t cum = 0; int x = 255;
            for (; x > 0; --x) { if (cum + part[x] >= K) break; cum += part[x]; }
            sTlo = (P << TSHIFT) | (((uint32_t)x) << (TSHIFT - 8));
        }
        __syncthreads();
    }
    if (tid == 0) { thr[img * 2 + 0] = sTlo; thr[img * 2 + 1] = sThi; }
}

// ============ Kernel 2: two-way compaction, 20 blocks/image, block-aggregated atomics ============
__global__ void __launch_bounds__(1024) k_compact(const float* __restrict__ logits,
                                                  const uint32_t* __restrict__ thr,
                                                  uint32_t* __restrict__ cnt,
                                                  ull* __restrict__ keys) {
    int img = blockIdx.y;
    const int tid = threadIdx.x;
    const int lane = tid & 63;
    __shared__ uint32_t sA, sB, gA, gB;
    if (tid == 0) { sA = 0u; sB = 0u; }
    __syncthreads();
    const uint32_t Tlo = thr[img * 2 + 0], Thi = thr[img * 2 + 1];
    const float* lg = logits + (size_t)img * NQC;
    const int base = blockIdx.x * 4096 + tid;

    uint32_t ukey[4]; bool fa[4], fb[4];
    uint32_t belowA[4], belowB[4], tAr[4], tBr[4];
    uint32_t TA = 0u, TB = 0u;
    #pragma unroll
    for (int r = 0; r < 4; ++r) {
        int i = base + r * 1024;
        uint32_t u = 0u; bool a = false, b = false;
        if (i < NQC) {
            u = fkey(lg[i]);
            a = (u >= Thi);
            b = !a && (u >= Tlo);
        }
        ukey[r] = u; fa[r] = a; fb[r] = b;
        ull ma = __ballot(a), mb = __ballot(b);
        belowA[r] = (uint32_t)__popcll(ma & ((1ull << lane) - 1ull));
        belowB[r] = (uint32_t)__popcll(mb & ((1ull << lane) - 1ull));
        tAr[r] = (uint32_t)__popcll(ma);
        tBr[r] = (uint32_t)__popcll(mb);
        TA += tAr[r]; TB += tBr[r];
    }
    uint32_t wbA = 0u, wbB = 0u;
    if (lane == 0) {
        if (TA) wbA = atomicAdd(&sA, TA);
        if (TB) wbB = atomicAdd(&sB, TB);
    }
    wbA = __shfl(wbA, 0, 64);
    wbB = __shfl(wbB, 0, 64);
    __syncthreads();
    if (tid == 0) {
        gA = sA ? atomicAdd(&cnt[img * CNTS + 0], sA) : 0u;
        gB = sB ? atomicAdd(&cnt[img * CNTS + 1], sB) : 0u;
    }
    __syncthreads();
    ull* kI = keys + (size_t)img * KSTRIDE;
    uint32_t preA = 0u, preB = 0u;
    #pragma unroll
    for (int r = 0; r < 4; ++r) {
        int i = base + r * 1024;
        ull kv = ((ull)ukey[r] << 32) | (ull)(0xFFFFFFFFu - (uint32_t)i);
        if (fa[r]) { uint32_t p = gA + wbA + preA + belowA[r]; if (p < SEGA) kI[p] = kv; }
        if (fb[r]) { uint32_t p = gB + wbB + preB + belowB[r]; if (p < SEGB) kI[SEGA + p] = kv; }
        preA += tAr[r]; preB += tBr[r];
    }
}

// ============ Kernel 3: bitonic sort of 3 runs of 4096 (desc), zero-padded ============
__global__ void __launch_bounds__(1024) k_sortrun(ull* __restrict__ keys,
                                                  const uint32_t* __restrict__ cnt) {
    int img = blockIdx.y;
    int run = blockIdx.x;
    const int tid = threadIdx.x;
    uint32_t cntA = cnt[img * CNTS + 0]; if (cntA > SEGA) cntA = SEGA;
    uint32_t cntB = cnt[img * CNTS + 1]; if (cntB > SEGB) cntB = SEGB;
    int n = (run == 0) ? ((cntA < RUNSZ) ? (int)cntA : RUNSZ)
          : (run == 1) ? ((cntA > RUNSZ) ? (int)(cntA - RUNSZ) : 0)
                       : (int)cntB;
    ull* base = keys + (size_t)img * KSTRIDE + (size_t)run * RUNSZ;
    __shared__ ull sh[RUNSZ];   // 32 KB
    for (int i = tid; i < RUNSZ; i += 1024) sh[i] = (i < n) ? base[i] : 0ull;
    __syncthreads();
    for (int k = 2; k <= RUNSZ; k <<= 1) {
        for (int j = k >> 1; j > 0; j >>= 1) {
            for (int t = tid; t < RUNSZ / 2; t += 1024) {
                int i = ((t & ~(j - 1)) << 1) | (t & (j - 1));
                int ixj = i | j;
                ull a = sh[i], b = sh[ixj];
                bool sw = ((i & k) == 0) ? (a < b) : (a > b);
                if (sw) { sh[i] = b; sh[ixj] = a; }
            }
            __syncthreads();
        }
    }
    for (int i = tid; i < RUNSZ; i += 1024) base[i] = sh[i];
}

// ============ Kernel 4: 3-way rank merge -> exact sorted top[PRE]; class counts + max coord ============
__global__ void __launch_bounds__(256) k_merge(const ull* __restrict__ keys,
                                               const float* __restrict__ pred_boxes,
                                               const float* __restrict__ target_sizes,
                                               ull* __restrict__ top,
                                               uint32_t* __restrict__ ccnt_g,
                                               uint32_t* __restrict__ mxkey) {
    int img = blockIdx.y;
    int e = blockIdx.x * 256 + threadIdx.x;    // [0, KSTRIDE)
    const int tid = threadIdx.x;
    const ull* kI = keys + (size_t)img * KSTRIDE;
    __shared__ uint32_t smx[256];
    uint32_t lm = 0u;
    ull x = kI[e];
    if (x != 0ull) {
        int run = e >> 12;
        int pos = e & (RUNSZ - 1);
        int rank = pos;
        #pragma unroll
        for (int s = 0; s < RUNS; ++s) {
            if (s != run) {
                const ull* o = kI + s * RUNSZ;
                int lo = 0, hi = RUNSZ;
                while (lo < hi) {
                    int mid = (lo + hi) >> 1;
                    if (o[mid] > x) lo = mid + 1; else hi = mid;
                }
                rank += lo;
            }
        }
        if (rank < PRE) {
            top[(size_t)img * PRE + rank] = x;
            uint32_t f = ~(uint32_t)x;
            uint32_t q = qclamp(f / NC);
            uint32_t c = f - (f / NC) * NC;
            atomicAdd(&ccnt_g[img * NC + (c % NC)], 1u);
            const float* pb = pred_boxes + (size_t)img * NQ * 4;
            const float ih = target_sizes[img * 2 + 0];
            const float iw = target_sizes[img * 2 + 1];
            float cx = pb[q * 4 + 0], cy = pb[q * 4 + 1], w = pb[q * 4 + 2], h = pb[q * 4 + 3];
            float x1 = (cx - 0.5f * w) * iw;
            float y1 = (cy - 0.5f * h) * ih;
            float x2 = (cx + 0.5f * w) * iw;
            float y2 = (cy + 0.5f * h) * ih;
            float m = fmaxf(fmaxf(x1, y1), fmaxf(x2, y2));
            lm = fkey(m);
        }
    }
    smx[tid] = lm;
    __syncthreads();
    for (int s = 128; s > 0; s >>= 1) {
        if (tid < s) { uint32_t o = smx[tid + s]; if (o > smx[tid]) smx[tid] = o; }
        __syncthreads();
    }
    if (tid == 0 && smx[0]) atomicMax(&mxkey[img], smx[0]);
}

// ============ Kernel 5: windowed greedy NMS, wave-parallel acceptance, class buckets ============
// Cross-class suppression provably impossible (offset bands: inter <= area/4 => IoU <= 1/3
// < 0.7): suppression scans only accepted candidates' class buckets. Conflict matrix for
// the 8-candidate window computed by 64 lanes (one IoU each) + ballot, not 64 IoU/thread.
__global__ void __launch_bounds__(1024) k_nms(const ull* __restrict__ top,
                                              const float* __restrict__ pred_boxes,
                                              const float* __restrict__ target_sizes,
                                              const uint32_t* __restrict__ ccnt_g,
                                              const uint32_t* __restrict__ mxkey,
                                              float* __restrict__ out) {
    int img = blockIdx.x;
    const int tid = threadIdx.x;
    __shared__ uint32_t fidx[PRE];          // 40000 B
    __shared__ unsigned short clist[PRE];   // 20000 B
    __shared__ uint32_t actw[WPRE];
    __shared__ uint32_t ccnt[NC];
    __shared__ uint32_t cstart[NC + 1];
    __shared__ uint32_t cfill[NC];
    __shared__ float sOffD;
    __shared__ int   s_cand[K_WIN];
    __shared__ float s_cx1[K_WIN], s_cy1[K_WIN], s_cx2[K_WIN], s_cy2[K_WIN], s_car[K_WIN];
    __shared__ int   s_ccl[K_WIN], s_cbs[K_WIN], s_cbe[K_WIN];

    const float ih = target_sizes[img * 2 + 0];
    const float iw = target_sizes[img * 2 + 1];
    const float* pb = pred_boxes + (size_t)img * NQ * 4;
    const ull* tp = top + (size_t)img * PRE;

    // Phase 1: pure loads (boxes/max/class-counts precomputed in k_merge)
    #pragma unroll
    for (int k = 0; k < 10; ++k) {
        int r = tid + k * 1024;
        if (r < PRE) fidx[r] = ~(uint32_t)tp[r];
    }
    for (int c = tid; c < NC; c += 1024) ccnt[c] = ccnt_g[img * NC + c];
    for (int wI = tid; wI < WPRE; wI += 1024) {
        int base = wI * 32;
        uint32_t m = 0xFFFFFFFFu;
        if (base + 32 > PRE) m = (base >= PRE) ? 0u : (0xFFFFFFFFu >> (base + 32 - PRE));
        actw[wI] = m;
    }
    __syncthreads();
    if (tid == 0) {
        sOffD = finv(mxkey[img]) + 1.0f;   // max_coord + 1
        uint32_t run = 0;
        for (int c = 0; c < NC; ++c) { cstart[c] = run; cfill[c] = run; run += ccnt[c]; }
        cstart[NC] = run;
    }
    __syncthreads();
    const float offD = sOffD;

    #pragma unroll
    for (int k = 0; k < 10; ++k) {
        int r = tid + k * 1024;
        if (r < PRE) {
            uint32_t c = fidx[r] % NC;
            uint32_t pos = atomicAdd(&cfill[c], 1u);
            if (pos < PRE) clist[pos] = (unsigned short)r;
        }
    }
    __syncthreads();

    // Phase 3: windowed greedy picks
    int wstart = 0;
    int pick = 0;
    const int lane = tid & 63;
    while (pick < POST) {
        while (wstart < WPRE && actw[wstart] == 0u) ++wstart;   // uniform
        if (wstart >= WPRE) {
            uint32_t fi = fidx[0];
            uint32_t qi = qclamp(fi / NC);
            uint32_t ci = fi - (fi / NC) * NC;
            float cx = pb[qi * 4 + 0], cy = pb[qi * 4 + 1], w = pb[qi * 4 + 2], h = pb[qi * 4 + 3];
            float rx1 = (cx - 0.5f * w) * iw;
            float ry1 = (cy - 0.5f * h) * ih;
            float rx2 = (cx + 0.5f * w) * iw;
            float ry2 = (cy + 0.5f * h) * ih;
            ull key = tp[0];
            float score = 1.0f / (1.0f + expf(-finv((uint32_t)(key >> 32))));
            for (int p = pick + tid; p < POST; p += 1024) {
                out[img * POST + p] = score;
                out[BS * POST + img * POST + p] = (float)ci;
                float* ob = out + 2 * BS * POST + ((size_t)img * POST + p) * 4;
                ob[0] = rx1; ob[1] = ry1; ob[2] = rx2; ob[3] = ry2;
            }
            break;
        }

        // uniform scan: first up to K_WIN active indices (score order)
        int ncand = 0;
        int myr = -1;
        {
            int wI = wstart;
            uint32_t wbits = actw[wI];
            #pragma unroll
            for (int j = 0; j < K_WIN; ++j) {
                while (wbits == 0u && wI + 1 < WPRE) { ++wI; wbits = actw[wI]; }
                if (wbits) {
                    int r = wI * 32 + (__ffs(wbits) - 1);
                    wbits &= wbits - 1u;
                    if (tid == 0) s_cand[j] = r;
                    if (tid == j) myr = r;
                    ++ncand;
                }
            }
        }

        if (tid < ncand) {
            uint32_t fi = fidx[myr];
            uint32_t q = qclamp(fi / NC);
            int c = (int)(fi - (fi / NC) * NC);
            float cx = pb[q * 4 + 0], cy = pb[q * 4 + 1], w = pb[q * 4 + 2], h = pb[q * 4 + 3];
            float x1 = (cx - 0.5f * w) * iw;
            float y1 = (cy - 0.5f * h) * ih;
            float x2 = (cx + 0.5f * w) * iw;
            float y2 = (cy + 0.5f * h) * ih;
            float o = (float)c * offD;
            float a1 = x1 + o, b1 = y1 + o, a2 = x2 + o, b2 = y2 + o;
            s_cx1[tid] = a1; s_cy1[tid] = b1; s_cx2[tid] = a2; s_cy2[tid] = b2;
            s_car[tid] = (a2 - a1) * (b2 - b1);
            s_ccl[tid] = c;
            s_cbs[tid] = (int)cstart[(c >= 0 && c < NC) ? c : 0];
            s_cbe[tid] = (int)cstart[((c >= 0 && c < NC) ? c : 0) + 1];
        }
        __syncthreads();

        // wave-parallel conflict matrix: lane l -> pair (j=l>>3, m=l&7), m<j only.
        // Stale LDS beyond ncand is harmless: rows for j>=ncand are never used.
        bool conf = false;
        {
            int pj = lane >> 3, pm = lane & 7;
            if (pm < pj && pj < ncand) {
                float xx1 = fmaxf(s_cx1[pm], s_cx1[pj]);
                float yy1 = fmaxf(s_cy1[pm], s_cy1[pj]);
                float xx2 = fminf(s_cx2[pm], s_cx2[pj]);
                float yy2 = fminf(s_cy2[pm], s_cy2[pj]);
                float inter = fmaxf(xx2 - xx1, 0.0f) * fmaxf(yy2 - yy1, 0.0f);
                float uni = (s_car[pm] + s_car[pj]) - inter;
                float iou = inter / fmaxf(uni, 1e-9f);
                conf = !(iou <= 0.7f);
            }
        }
        ull cmask = __ballot(conf);   // identical in every wave
        uint32_t accMask = 0u;
        int A = 0;
        const int maxA = POST - pick;
        #pragma unroll
        for (int jj = 0; jj < K_WIN; ++jj) {
            uint32_t row = (uint32_t)(cmask >> (jj * 8)) & 0xFFu;
            if (jj < ncand && A < maxA && ((row & accMask) == 0u)) { accMask |= (1u << jj); ++A; }
        }

        // outputs (pick order = candidate order among accepted)
        #pragma unroll
        for (int j = 0; j < K_WIN; ++j) {
            if ((accMask >> j) & 1u) {
                int ord = __popc(accMask & ((1u << j) - 1u));
                if (tid == ord) {
                    int r = s_cand[j];
                    uint32_t fi = fidx[r];
                    uint32_t qi = qclamp(fi / NC);
                    uint32_t ci = fi - (fi / NC) * NC;
                    float cx = pb[qi * 4 + 0], cy = pb[qi * 4 + 1], w = pb[qi * 4 + 2], h = pb[qi * 4 + 3];
                    float rx1 = (cx - 0.5f * w) * iw;
                    float ry1 = (cy - 0.5f * h) * ih;
                    float rx2 = (cx + 0.5f * w) * iw;
                    float ry2 = (cy + 0.5f * h) * ih;
                    ull key = tp[r];
                    float score = 1.0f / (1.0f + expf(-finv((uint32_t)(key >> 32))));
                    int p = pick + ord;
                    out[img * POST + p] = score;
                    out[BS * POST + img * POST + p] = (float)ci;
                    float* ob = out + 2 * BS * POST + ((size_t)img * POST + p) * 4;
                    ob[0] = rx1; ob[1] = ry1; ob[2] = rx2; ob[3] = ry2;
                }
            }
        }

        // flattened suppression over (accepted j, bucket item): total ~<= 8*130 <= 1024
        int startj[K_WIN];
        int tot = 0;
        #pragma unroll
        for (int j = 0; j < K_WIN; ++j) {
            startj[j] = tot;
            if ((accMask >> j) & 1u) tot += s_cbe[j] - s_cbs[j];
        }
        for (int t2 = tid; t2 < tot; t2 += 1024) {
            int j = 0;
            #pragma unroll
            for (int jj = 1; jj < K_WIN; ++jj) if (startj[jj] <= t2) j = jj;
            int r2 = clist[s_cbs[j] + (t2 - startj[j])];
            if (actw[r2 >> 5] & (1u << (r2 & 31))) {
                float o = (float)s_ccl[j] * offD;
                uint32_t f2 = fidx[r2];
                uint32_t q2 = qclamp(f2 / NC);
                float cx = pb[q2 * 4 + 0], cy = pb[q2 * 4 + 1], w = pb[q2 * 4 + 2], h = pb[q2 * 4 + 3];
                float jx1 = (cx - 0.5f * w) * iw + o;
                float jy1 = (cy - 0.5f * h) * ih + o;
                float jx2 = (cx + 0.5f * w) * iw + o;
                float jy2 = (cy + 0.5f * h) * ih + o;
                float arj = (jx2 - jx1) * (jy2 - jy1);
                float xx1 = fmaxf(s_cx1[j], jx1);
                float yy1 = fmaxf(s_cy1[j], jy1);
                float xx2 = fminf(s_cx2[j], jx2);
                float yy2 = fminf(s_cy2[j], jy2);
                float inter = fmaxf(xx2 - xx1, 0.0f) * fmaxf(yy2 - yy1, 0.0f);
                float uni = (s_car[j] + arj) - inter;
                float iou = inter / fmaxf(uni, 1e-9f);
                if (!(iou <= 0.7f)) atomicAnd(&actw[r2 >> 5], ~(1u << (r2 & 31)));
            }
        }
        pick += A;
        __syncthreads();
    }
}

extern "C" void kernel_launch(void* const* d_in, const int* in_sizes, int n_in,
                              void* d_out, int out_size, void* d_ws, size_t ws_size,
                              hipStream_t stream) {
    const float* logits = (const float*)d_in[0];
    const float* boxes  = (const float*)d_in[1];
    const float* tsizes = (const float*)d_in[2];
    float* out = (float*)d_out;

    char* ws = (char*)d_ws;
    uint32_t* cnt    = (uint32_t*)(ws + WS_CNT);
    uint32_t* mxk    = (uint32_t*)(ws + WS_MX);
    uint32_t* ccnt_g = (uint32_t*)(ws + WS_CCNT);
    uint32_t* thr    = (uint32_t*)(ws + WS_THR);
    ull* keys = (ull*)(ws + WS_KEYS);
    ull* top  = (ull*)(ws + WS_TOP);

    k_select<<<BS, 1024, 0, stream>>>(logits, cnt, ccnt_g, mxk, thr);
    k_compact<<<dim3(20, BS), 1024, 0, stream>>>(logits, thr, cnt, keys);
    k_sortrun<<<dim3(RUNS, BS), 1024, 0, stream>>>(keys, cnt);
    k_merge<<<dim3(KSTRIDE / 256, BS), 256, 0, stream>>>(keys, boxes, tsizes, top, ccnt_g, mxk);
    k_nms<<<BS, 1024, 0, stream>>>(top, boxes, tsizes, ccnt_g, mxk, out);
}

// Round 8
// 255.264 us; speedup vs baseline: 1.3736x; 1.1562x over previous
//
#include <hip/hip_runtime.h>
#include <cstdint>

#pragma clang fp contract(off)

#define BS   128
#define NQ   900
#define NC   91
#define NQC  (NQ * NC)   // 81900
#define Q4   (NQC / 4)   // 20475
#define PRE  10000
#define POST 100
#define SEGA 8192
#define SEGB 4096
#define RUNSZ 4096
#define RUNS 3
#define KSTRIDE (RUNS * RUNSZ)    // 12288 keys per image
#define CNTS 16
#define TBITS 13
#define TBINS (1 << TBITS)
#define TSHIFT (32 - TBITS)
#define WPRE 320                  // ceil(PRE/32) words for active bitmask
#define K_WIN 8

typedef unsigned long long ull;

// ---- workspace layout (bytes); zeroing done in k_select ----
#define WS_CNT    0            // 128*CNTS*4 = 8 KB
#define WS_THR    8192         // 128*2*4 = 1 KB
#define WS_KEYS   16384        // 128*12288*8 = 12.6 MB

__device__ __forceinline__ uint32_t fkey(float f) {
    uint32_t b = __float_as_uint(f);
    return (b & 0x80000000u) ? ~b : (b | 0x80000000u);
}
// defensive clamp: valid keys give q < NQ; turns capacity bugs into wrong-value not fault
__device__ __forceinline__ uint32_t qclamp(uint32_t q) { return (q < NQ) ? q : (NQ - 1); }

// ============ Kernel 1: per-image LDS histogram -> thresholds; zero counters ============
// T_lo: largest bin boundary with suffix >= PRE; T_hi: smallest with suffix <= SEGA.
// Segment A: key >= T_hi (<= 8192). Segment B: [T_lo, T_hi) (~1940 typ, <= 4096;
// rare 8-bit refine if the straddling bin is fat). A-keys all > B-keys.
__global__ void __launch_bounds__(1024) k_select(const float* __restrict__ logits,
                                                 uint32_t* __restrict__ cnt,
                                                 uint32_t* __restrict__ thr) {
    int img = blockIdx.x;
    const int tid = threadIdx.x;
    __shared__ uint32_t hist[TBINS];   // 32 KB
    __shared__ uint32_t part[1024];
    __shared__ uint32_t part2[32];
    __shared__ uint32_t sTlo, sThi, sBlo, sCumAboveLo, sM, sM1;
    for (int i = tid; i < TBINS; i += 1024) hist[i] = 0u;
    if (tid == 0) { cnt[img * CNTS + 0] = 0u; cnt[img * CNTS + 1] = 0u; }
    __syncthreads();
    const float4* lg4 = (const float4*)(logits + (size_t)img * NQC);
    for (int i = tid; i < Q4; i += 1024) {
        float4 v = lg4[i];
        atomicAdd(&hist[fkey(v.x) >> TSHIFT], 1u);
        atomicAdd(&hist[fkey(v.y) >> TSHIFT], 1u);
        atomicAdd(&hist[fkey(v.z) >> TSHIFT], 1u);
        atomicAdd(&hist[fkey(v.w) >> TSHIFT], 1u);
    }
    __syncthreads();
    {
        uint32_t s = 0;
        int base = tid * (TBINS / 1024);
        for (int j = 0; j < TBINS / 1024; ++j) s += hist[base + j];
        part[tid] = s;
    }
    __syncthreads();
    if (tid < 32) {
        uint32_t s2 = 0;
        for (int j = 0; j < 32; ++j) s2 += part[tid * 32 + j];
        part2[tid] = s2;
    }
    __syncthreads();
    if (tid == 0) {
        uint32_t cum = 0; int w = 31;
        for (; w > 0; --w) { if (cum + part2[w] >= PRE) break; cum += part2[w]; }
        int t = w * 32 + 31;
        for (; t > w * 32; --t) { if (cum + part[t] >= PRE) break; cum += part[t]; }
        int b = t * (TBINS / 1024) + (TBINS / 1024 - 1);
        for (; b > t * (TBINS / 1024); --b) { if (cum + hist[b] >= PRE) break; cum += hist[b]; }
        sBlo = (uint32_t)b;
        sCumAboveLo = cum;
        sM = cum + hist[b];
        sTlo = ((uint32_t)b) << TSHIFT;
        uint32_t cum2 = 0; int w2 = 31;
        for (; w2 >= 0; --w2) { if (cum2 + part2[w2] > SEGA) break; cum2 += part2[w2]; }
        int t2 = w2 * 32 + 31;
        for (; t2 >= w2 * 32; --t2) { if (cum2 + part[t2] > SEGA) break; cum2 += part[t2]; }
        int b2 = t2 * (TBINS / 1024) + (TBINS / 1024 - 1);
        for (; b2 >= t2 * (TBINS / 1024); --b2) { if (cum2 + hist[b2] > SEGA) break; cum2 += hist[b2]; }
        sM1 = cum2;
        sThi = (b2 >= TBINS - 1) ? 0xFFFFFFFFu : (((uint32_t)(b2 + 1)) << TSHIFT);
    }
    __syncthreads();
    if (sM - sM1 > SEGB) {   // block-uniform rare fallback: refine Tlo by 8 bits
        uint32_t P = sBlo;
        for (int i = tid; i < 256; i += 1024) part[i] = 0u;
        __syncthreads();
        for (int i = tid; i < Q4; i += 1024) {
            float4 v = lg4[i];
            uint32_t u;
            u = fkey(v.x); if ((u >> TSHIFT) == P) atomicAdd(&part[(u >> (TSHIFT - 8)) & 0xFFu], 1u);
            u = fkey(v.y); if ((u >> TSHIFT) == P) atomicAdd(&part[(u >> (TSHIFT - 8)) & 0xFFu], 1u);
            u = fkey(v.z); if ((u >> TSHIFT) == P) atomicAdd(&part[(u >> (TSHIFT - 8)) & 0xFFu], 1u);
            u = fkey(v.w); if ((u >> TSHIFT) == P) atomicAdd(&part[(u >> (TSHIFT - 8)) & 0xFFu], 1u);
        }
        __syncthreads();
        if (tid == 0) {
            uint32_t K = PRE - sCumAboveLo;
            uint32_t cum = 0; int x = 255;
            for (; x > 0; --x) { if (cum + part[x] >= K) break; cum += part[x]; }
            sTlo = (P << TSHIFT) | (((uint32_t)x) << (TSHIFT - 8));
        }
        __syncthreads();
    }
    if (tid == 0) { thr[img * 2 + 0] = sTlo; thr[img * 2 + 1] = sThi; }
}

// ============ Kernel 2: two-way compaction, 20 blocks/image, block-aggregated atomics ============
__global__ void __launch_bounds__(1024) k_compact(const float* __restrict__ logits,
                                                  const uint32_t* __restrict__ thr,
                                                  uint32_t* __restrict__ cnt,
                                                  ull* __restrict__ keys) {
    int img = blockIdx.y;
    const int tid = threadIdx.x;
    const int lane = tid & 63;
    __shared__ uint32_t sA, sB, gA, gB;
    if (tid == 0) { sA = 0u; sB = 0u; }
    __syncthreads();
    const uint32_t Tlo = thr[img * 2 + 0], Thi = thr[img * 2 + 1];
    const float* lg = logits + (size_t)img * NQC;
    const int base = blockIdx.x * 4096 + tid;

    uint32_t ukey[4]; bool fa[4], fb[4];
    uint32_t belowA[4], belowB[4], tAr[4], tBr[4];
    uint32_t TA = 0u, TB = 0u;
    #pragma unroll
    for (int r = 0; r < 4; ++r) {
        int i = base + r * 1024;
        uint32_t u = 0u; bool a = false, b = false;
        if (i < NQC) {
            u = fkey(lg[i]);
            a = (u >= Thi);
            b = !a && (u >= Tlo);
        }
        ukey[r] = u; fa[r] = a; fb[r] = b;
        ull ma = __ballot(a), mb = __ballot(b);
        belowA[r] = (uint32_t)__popcll(ma & ((1ull << lane) - 1ull));
        belowB[r] = (uint32_t)__popcll(mb & ((1ull << lane) - 1ull));
        tAr[r] = (uint32_t)__popcll(ma);
        tBr[r] = (uint32_t)__popcll(mb);
        TA += tAr[r]; TB += tBr[r];
    }
    uint32_t wbA = 0u, wbB = 0u;
    if (lane == 0) {
        if (TA) wbA = atomicAdd(&sA, TA);
        if (TB) wbB = atomicAdd(&sB, TB);
    }
    wbA = __shfl(wbA, 0, 64);
    wbB = __shfl(wbB, 0, 64);
    __syncthreads();
    if (tid == 0) {
        gA = sA ? atomicAdd(&cnt[img * CNTS + 0], sA) : 0u;
        gB = sB ? atomicAdd(&cnt[img * CNTS + 1], sB) : 0u;
    }
    __syncthreads();
    ull* kI = keys + (size_t)img * KSTRIDE;
    uint32_t preA = 0u, preB = 0u;
    #pragma unroll
    for (int r = 0; r < 4; ++r) {
        int i = base + r * 1024;
        ull kv = ((ull)ukey[r] << 32) | (ull)(0xFFFFFFFFu - (uint32_t)i);
        if (fa[r]) { uint32_t p = gA + wbA + preA + belowA[r]; if (p < SEGA) kI[p] = kv; }
        if (fb[r]) { uint32_t p = gB + wbB + preB + belowB[r]; if (p < SEGB) kI[SEGA + p] = kv; }
        preA += tAr[r]; preB += tBr[r];
    }
}

// ============ Kernel 3: bitonic sort of 3 runs of 4096 (desc), zero-padded ============
__global__ void __launch_bounds__(1024) k_sortrun(ull* __restrict__ keys,
                                                  const uint32_t* __restrict__ cnt) {
    int img = blockIdx.y;
    int run = blockIdx.x;
    const int tid = threadIdx.x;
    uint32_t cntA = cnt[img * CNTS + 0]; if (cntA > SEGA) cntA = SEGA;
    uint32_t cntB = cnt[img * CNTS + 1]; if (cntB > SEGB) cntB = SEGB;
    int n = (run == 0) ? ((cntA < RUNSZ) ? (int)cntA : RUNSZ)
          : (run == 1) ? ((cntA > RUNSZ) ? (int)(cntA - RUNSZ) : 0)
                       : (int)cntB;
    ull* base = keys + (size_t)img * KSTRIDE + (size_t)run * RUNSZ;
    __shared__ ull sh[RUNSZ];   // 32 KB
    for (int i = tid; i < RUNSZ; i += 1024) sh[i] = (i < n) ? base[i] : 0ull;
    __syncthreads();
    for (int k = 2; k <= RUNSZ; k <<= 1) {
        for (int j = k >> 1; j > 0; j >>= 1) {
            for (int t = tid; t < RUNSZ / 2; t += 1024) {
                int i = ((t & ~(j - 1)) << 1) | (t & (j - 1));
                int ixj = i | j;
                ull a = sh[i], b = sh[ixj];
                bool sw = ((i & k) == 0) ? (a < b) : (a > b);
                if (sw) { sh[i] = b; sh[ixj] = a; }
            }
            __syncthreads();
        }
    }
    for (int i = tid; i < RUNSZ; i += 1024) base[i] = sh[i];
}

// ============ Kernel 4: LDS rank-merge + windowed greedy NMS (class buckets) ============
// Runs 0,1 (segment A) merged by LDS binary search: rank = pos + count(other run > x).
// Segment B concatenates below A (all A-keys > all B-keys): rank = cntA + pos.
// Cross-class suppression provably impossible (offset bands: inter <= area/4 => IoU <= 1/3
// < 0.7): suppression scans only accepted candidates' class buckets. Window conflict
// matrix computed wave-parallel (one IoU per lane + ballot).
__global__ void __launch_bounds__(1024) k_nms(const ull* __restrict__ keys,
                                              const uint32_t* __restrict__ cnt,
                                              const float* __restrict__ logits,
                                              const float* __restrict__ pred_boxes,
                                              const float* __restrict__ target_sizes,
                                              float* __restrict__ out) {
    int img = blockIdx.x;
    const int tid = threadIdx.x;
    const int lane = tid & 63;
    __shared__ ull shA[SEGA];               // 64 KB: runs 0+1 (sorted desc, zero-padded)
    __shared__ uint32_t fidx[PRE];          // 40000 B
    __shared__ unsigned short clist[PRE];   // 20000 B
    __shared__ uint32_t actw[WPRE];
    __shared__ uint32_t ccnt[NC];
    __shared__ uint32_t cstart[NC + 1];
    __shared__ uint32_t cfill[NC];
    __shared__ uint32_t smx[16];
    __shared__ float sOffD;
    __shared__ int   s_cand[K_WIN];
    __shared__ float s_cx1[K_WIN], s_cy1[K_WIN], s_cx2[K_WIN], s_cy2[K_WIN], s_car[K_WIN];
    __shared__ int   s_ccl[K_WIN], s_cbs[K_WIN], s_cbe[K_WIN];

    const float ih = target_sizes[img * 2 + 0];
    const float iw = target_sizes[img * 2 + 1];
    const float* pb = pred_boxes + (size_t)img * NQ * 4;
    const float* lg = logits + (size_t)img * NQC;
    const ull* kI = keys + (size_t)img * KSTRIDE;
    uint32_t cntA = cnt[img * CNTS + 0]; if (cntA > SEGA) cntA = SEGA;
    uint32_t cntB = cnt[img * CNTS + 1]; if (cntB > SEGB) cntB = SEGB;

    // Phase 0: load A runs into LDS; init masks/counters
    #pragma unroll
    for (int k = 0; k < 8; ++k) shA[tid + k * 1024] = kI[tid + k * 1024];
    for (int c = tid; c < NC; c += 1024) ccnt[c] = 0u;
    for (int wI = tid; wI < WPRE; wI += 1024) {
        int base = wI * 32;
        uint32_t m = 0xFFFFFFFFu;
        if (base + 32 > PRE) m = (base >= PRE) ? 0u : (0xFFFFFFFFu >> (base + 32 - PRE));
        actw[wI] = m;
    }
    __syncthreads();

    // Phase 1: rank A elements (binary search in LDS), concat B; fidx scatter,
    // class histogram, max scaled coord over the exact top-PRE set.
    uint32_t lmx = 0u;   // fkey-mapped max coordinate
    #pragma unroll
    for (int k = 0; k < 8; ++k) {
        int e = tid + k * 1024;
        ull x = shA[e];
        if (x != 0ull) {
            int run = e >> 12;               // 0 or 1
            int pos = e & (RUNSZ - 1);
            const ull* other = &shA[run ? 0 : RUNSZ];
            int lo = 0, hi = RUNSZ;
            while (lo < hi) {                // count of other-run elements > x
                int mid = (lo + hi) >> 1;
                if (other[mid] > x) lo = mid + 1; else hi = mid;
            }
            int rank = pos + lo;             // rank < cntA <= 8192 < PRE always
            uint32_t f = ~(uint32_t)x;
            fidx[rank] = f;
            uint32_t q = qclamp(f / NC);
            atomicAdd(&ccnt[(f - (f / NC) * NC) % NC], 1u);
            float cx = pb[q * 4 + 0], cy = pb[q * 4 + 1], w = pb[q * 4 + 2], h = pb[q * 4 + 3];
            float x1 = (cx - 0.5f * w) * iw;
            float y1 = (cy - 0.5f * h) * ih;
            float x2 = (cx + 0.5f * w) * iw;
            float y2 = (cy + 0.5f * h) * ih;
            uint32_t km = fkey(fmaxf(fmaxf(x1, y1), fmaxf(x2, y2)));
            if (km > lmx) lmx = km;
        }
    }
    #pragma unroll
    for (int k = 0; k < 4; ++k) {
        int p = tid + k * 1024;              // B position
        int rank = (int)cntA + p;
        if (p < (int)cntB && rank < PRE) {
            ull x = kI[SEGA + p];
            if (x != 0ull) {
                uint32_t f = ~(uint32_t)x;
                fidx[rank] = f;
                uint32_t q = qclamp(f / NC);
                atomicAdd(&ccnt[(f - (f / NC) * NC) % NC], 1u);
                float cx = pb[q * 4 + 0], cy = pb[q * 4 + 1], w = pb[q * 4 + 2], h = pb[q * 4 + 3];
                float x1 = (cx - 0.5f * w) * iw;
                float y1 = (cy - 0.5f * h) * ih;
                float x2 = (cx + 0.5f * w) * iw;
                float y2 = (cy + 0.5f * h) * ih;
                uint32_t km = fkey(fmaxf(fmaxf(x1, y1), fmaxf(x2, y2)));
                if (km > lmx) lmx = km;
            }
        }
    }
    for (int off = 32; off > 0; off >>= 1) {
        uint32_t o = (uint32_t)__shfl_down((int)lmx, off, 64);
        if (o > lmx) lmx = o;
    }
    if (lane == 0) smx[tid >> 6] = lmx;
    __syncthreads();
    if (tid == 0) {
        uint32_t m = smx[0];
        for (int wv = 1; wv < 16; ++wv) if (smx[wv] > m) m = smx[wv];
        uint32_t b = (m & 0x80000000u) ? (m & 0x7FFFFFFFu) : ~m;
        sOffD = __uint_as_float(b) + 1.0f;   // max_coord + 1
        uint32_t run = 0;
        for (int c = 0; c < NC; ++c) { cstart[c] = run; cfill[c] = run; run += ccnt[c]; }
        cstart[NC] = run;
    }
    __syncthreads();
    const float offD = sOffD;

    // Phase 2: class-bucket scatter (order within bucket irrelevant)
    #pragma unroll
    for (int k = 0; k < 10; ++k) {
        int r = tid + k * 1024;
        if (r < PRE) {
            uint32_t c = fidx[r] % NC;
            uint32_t pos = atomicAdd(&cfill[c], 1u);
            if (pos < PRE) clist[pos] = (unsigned short)r;
        }
    }
    __syncthreads();

    // Phase 3: windowed greedy picks
    int wstart = 0;
    int pick = 0;
    while (pick < POST) {
        while (wstart < WPRE && actw[wstart] == 0u) ++wstart;   // uniform
        if (wstart >= WPRE) {
            uint32_t fi = fidx[0];
            uint32_t qi = qclamp(fi / NC);
            uint32_t ci = fi - (fi / NC) * NC;
            float cx = pb[qi * 4 + 0], cy = pb[qi * 4 + 1], w = pb[qi * 4 + 2], h = pb[qi * 4 + 3];
            float rx1 = (cx - 0.5f * w) * iw;
            float ry1 = (cy - 0.5f * h) * ih;
            float rx2 = (cx + 0.5f * w) * iw;
            float ry2 = (cy + 0.5f * h) * ih;
            float score = 1.0f / (1.0f + expf(-lg[(fi < NQC) ? fi : 0]));
            for (int p = pick + tid; p < POST; p += 1024) {
                out[img * POST + p] = score;
                out[BS * POST + img * POST + p] = (float)ci;
                float* ob = out + 2 * BS * POST + ((size_t)img * POST + p) * 4;
                ob[0] = rx1; ob[1] = ry1; ob[2] = rx2; ob[3] = ry2;
            }
            break;
        }

        // uniform scan: first up to K_WIN active indices (score order)
        int ncand = 0;
        int myr = -1;
        {
            int wI = wstart;
            uint32_t wbits = actw[wI];
            #pragma unroll
            for (int j = 0; j < K_WIN; ++j) {
                while (wbits == 0u && wI + 1 < WPRE) { ++wI; wbits = actw[wI]; }
                if (wbits) {
                    int r = wI * 32 + (__ffs(wbits) - 1);
                    wbits &= wbits - 1u;
                    if (tid == 0) s_cand[j] = r;
                    if (tid == j) myr = r;
                    ++ncand;
                }
            }
        }

        if (tid < ncand) {
            uint32_t fi = fidx[myr];
            uint32_t q = qclamp(fi / NC);
            int c = (int)(fi - (fi / NC) * NC);
            float cx = pb[q * 4 + 0], cy = pb[q * 4 + 1], w = pb[q * 4 + 2], h = pb[q * 4 + 3];
            float x1 = (cx - 0.5f * w) * iw;
            float y1 = (cy - 0.5f * h) * ih;
            float x2 = (cx + 0.5f * w) * iw;
            float y2 = (cy + 0.5f * h) * ih;
            float o = (float)c * offD;
            float a1 = x1 + o, b1 = y1 + o, a2 = x2 + o, b2 = y2 + o;
            s_cx1[tid] = a1; s_cy1[tid] = b1; s_cx2[tid] = a2; s_cy2[tid] = b2;
            s_car[tid] = (a2 - a1) * (b2 - b1);
            s_ccl[tid] = c;
            s_cbs[tid] = (int)cstart[(c >= 0 && c < NC) ? c : 0];
            s_cbe[tid] = (int)cstart[((c >= 0 && c < NC) ? c : 0) + 1];
        }
        __syncthreads();

        // wave-parallel conflict matrix: lane l -> pair (j=l>>3, m=l&7), m<j only
        bool conf = false;
        {
            int pj = lane >> 3, pm = lane & 7;
            if (pm < pj && pj < ncand) {
                float xx1 = fmaxf(s_cx1[pm], s_cx1[pj]);
                float yy1 = fmaxf(s_cy1[pm], s_cy1[pj]);
                float xx2 = fminf(s_cx2[pm], s_cx2[pj]);
                float yy2 = fminf(s_cy2[pm], s_cy2[pj]);
                float inter = fmaxf(xx2 - xx1, 0.0f) * fmaxf(yy2 - yy1, 0.0f);
                float uni = (s_car[pm] + s_car[pj]) - inter;
                float iou = inter / fmaxf(uni, 1e-9f);
                conf = !(iou <= 0.7f);
            }
        }
        ull cmask = __ballot(conf);   // identical in every wave
        uint32_t accMask = 0u;
        int A = 0;
        const int maxA = POST - pick;
        #pragma unroll
        for (int jj = 0; jj < K_WIN; ++jj) {
            uint32_t row = (uint32_t)(cmask >> (jj * 8)) & 0xFFu;
            if (jj < ncand && A < maxA && ((row & accMask) == 0u)) { accMask |= (1u << jj); ++A; }
        }

        // outputs (pick order = candidate order among accepted)
        #pragma unroll
        for (int j = 0; j < K_WIN; ++j) {
            if ((accMask >> j) & 1u) {
                int ord = __popc(accMask & ((1u << j) - 1u));
                if (tid == ord) {
                    int r = s_cand[j];
                    uint32_t fi = fidx[r];
                    uint32_t qi = qclamp(fi / NC);
                    uint32_t ci = fi - (fi / NC) * NC;
                    float cx = pb[qi * 4 + 0], cy = pb[qi * 4 + 1], w = pb[qi * 4 + 2], h = pb[qi * 4 + 3];
                    float rx1 = (cx - 0.5f * w) * iw;
                    float ry1 = (cy - 0.5f * h) * ih;
                    float rx2 = (cx + 0.5f * w) * iw;
                    float ry2 = (cy + 0.5f * h) * ih;
                    float score = 1.0f / (1.0f + expf(-lg[(fi < NQC) ? fi : 0]));
                    int p = pick + ord;
                    out[img * POST + p] = score;
                    out[BS * POST + img * POST + p] = (float)ci;
                    float* ob = out + 2 * BS * POST + ((size_t)img * POST + p) * 4;
                    ob[0] = rx1; ob[1] = ry1; ob[2] = rx2; ob[3] = ry2;
                }
            }
        }

        // flattened suppression over (accepted j, bucket item)
        int startj[K_WIN];
        int tot = 0;
        #pragma unroll
        for (int j = 0; j < K_WIN; ++j) {
            startj[j] = tot;
            if ((accMask >> j) & 1u) tot += s_cbe[j] - s_cbs[j];
        }
        for (int t2 = tid; t2 < tot; t2 += 1024) {
            int j = 0;
            #pragma unroll
            for (int jj = 1; jj < K_WIN; ++jj) if (startj[jj] <= t2) j = jj;
            int r2 = clist[s_cbs[j] + (t2 - startj[j])];
            if (actw[r2 >> 5] & (1u << (r2 & 31))) {
                float o = (float)s_ccl[j] * offD;
                uint32_t f2 = fidx[r2];
                uint32_t q2 = qclamp(f2 / NC);
                float cx = pb[q2 * 4 + 0], cy = pb[q2 * 4 + 1], w = pb[q2 * 4 + 2], h = pb[q2 * 4 + 3];
                float jx1 = (cx - 0.5f * w) * iw + o;
                float jy1 = (cy - 0.5f * h) * ih + o;
                float jx2 = (cx + 0.5f * w) * iw + o;
                float jy2 = (cy + 0.5f * h) * ih + o;
                float arj = (jx2 - jx1) * (jy2 - jy1);
                float xx1 = fmaxf(s_cx1[j], jx1);
                float yy1 = fmaxf(s_cy1[j], jy1);
                float xx2 = fminf(s_cx2[j], jx2);
                float yy2 = fminf(s_cy2[j], jy2);
                float inter = fmaxf(xx2 - xx1, 0.0f) * fmaxf(yy2 - yy1, 0.0f);
                float uni = (s_car[j] + arj) - inter;
                float iou = inter / fmaxf(uni, 1e-9f);
                if (!(iou <= 0.7f)) atomicAnd(&actw[r2 >> 5], ~(1u << (r2 & 31)));
            }
        }
        pick += A;
        __syncthreads();
    }
}

extern "C" void kernel_launch(void* const* d_in, const int* in_sizes, int n_in,
                              void* d_out, int out_size, void* d_ws, size_t ws_size,
                              hipStream_t stream) {
    const float* logits = (const float*)d_in[0];
    const float* boxes  = (const float*)d_in[1];
    const float* tsizes = (const float*)d_in[2];
    float* out = (float*)d_out;

    char* ws = (char*)d_ws;
    uint32_t* cnt = (uint32_t*)(ws + WS_CNT);
    uint32_t* thr = (uint32_t*)(ws + WS_THR);
    ull* keys = (ull*)(ws + WS_KEYS);

    k_select<<<BS, 1024, 0, stream>>>(logits, cnt, thr);
    k_compact<<<dim3(20, BS), 1024, 0, stream>>>(logits, thr, cnt, keys);
    k_sortrun<<<dim3(RUNS, BS), 1024, 0, stream>>>(keys, cnt);
    k_nms<<<BS, 1024, 0, stream>>>(keys, cnt, logits, boxes, tsizes, out);
}